// Round 8
// baseline (109.962 us; speedup 1.0000x reference)
//
#include <hip/hip_runtime.h>
#include <math.h>

#define NRAYS 512
#define NSAMP 64
#define IMH 480
#define IMW 640
#define NFEAT 256
#define ZNEAR 0.7f
#define ZFAR 1.5f
#define KU1 288          // W1 row length (ushorts): k-map 0-8 meta, 9-15 zero, 16-271 feats, 272-287 zero
#define W1LO 36864       // ushort offset of W1 lo plane
#define W2OF 73728       // ushort offset of W2 hi plane
#define W2LO 16384       // relative ushort offset of W2 lo plane
#define H1S 132          // h1 packed row stride (u32): 16B-aligned, 2-way-bank

typedef __attribute__((ext_vector_type(8))) short bf16x8;
typedef __attribute__((ext_vector_type(4))) float f32x4;

__device__ __forceinline__ unsigned short bf16rne(float f) {
    unsigned int u = __builtin_bit_cast(unsigned int, f);
    unsigned int r = (u + 0x7FFFu + ((u >> 16) & 1u)) >> 16;
    return (unsigned short)r;
}
__device__ __forceinline__ float bf16tof(unsigned short h) {
    unsigned int u = ((unsigned int)h) << 16;
    return __builtin_bit_cast(float, u);
}
__device__ __forceinline__ unsigned int packsplit(float v) {
    const unsigned short h = bf16rne(v);
    const unsigned short l = bf16rne(v - bf16tof(h));
    return (((unsigned int)h) << 16) | (unsigned int)l;
}
__device__ __forceinline__ void splitpack(const float* f, bf16x8& hi, bf16x8& lo) {
    union { bf16x8 v; unsigned short u[8]; } H, L;
    #pragma unroll
    for (int i = 0; i < 8; ++i) {
        const unsigned short h = bf16rne(f[i]);
        H.u[i] = h;
        L.u[i] = bf16rne(f[i] - bf16tof(h));
    }
    hi = H.v; lo = L.v;
}
__device__ __forceinline__ void unpack8(uint4 a, uint4 b, bf16x8& hi, bf16x8& lo) {
    union { bf16x8 v; unsigned short u[8]; } H, L;
    const unsigned int w[8] = {a.x, a.y, a.z, a.w, b.x, b.y, b.z, b.w};
    #pragma unroll
    for (int i = 0; i < 8; ++i) {
        H.u[i] = (unsigned short)(w[i] >> 16);
        L.u[i] = (unsigned short)(w[i] & 0xFFFFu);
    }
    hi = H.v; lo = L.v;
}

// ---- prep: transpose + bf16-split W1 -> [128][288] (k-map above) and W2 -> [128][128] ----
__global__ __launch_bounds__(256)
void nerf_prep(const float* __restrict__ W1, const float* __restrict__ W2,
               unsigned short* __restrict__ wsu) {
    const int i = blockIdx.x * 256 + threadIdx.x;
    if (i < 36864) {
        const int n = i / KU1, k = i % KU1;
        float val = 0.0f;
        if (k < 9) val = W1[k * 128 + n];
        else if (k >= 16 && k < 272) val = W1[(k - 7) * 128 + n];
        const unsigned short h = bf16rne(val);
        wsu[n * KU1 + k] = h;
        wsu[W1LO + n * KU1 + k] = bf16rne(val - bf16tof(h));
    } else if (i < 53248) {
        const int j = i - 36864;
        const int n = j >> 7, k = j & 127;
        const float val = W2[k * 128 + n];
        const unsigned short h = bf16rne(val);
        wsu[W2OF + n * 128 + k] = h;
        wsu[W2OF + W2LO + n * 128 + k] = bf16rne(val - bf16tof(h));
    }
}

// ---- main: block = (ray,view), 256 thr = 4 waves, wave owns 16 samples.
// kc-outer MLP: acc[8 nt] resident, ONE kc's A-fragment live at a time; lane
// (l15,lg) bilerps its own 8 dims directly from feats (no staging LDS).
// buildA(kc+1) issues loads before kc's 24-MFMA sweep -> latency hidden.
__global__ __launch_bounds__(256, 4)
void nerf_main(const float* __restrict__ rayo,
               const float* __restrict__ rayd,
               const float* __restrict__ images,
               const float* __restrict__ intr,
               const float* __restrict__ einv,
               const float* __restrict__ feats,
               const float* __restrict__ b1,
               const float* __restrict__ b2,
               const float* __restrict__ Wr,
               const unsigned short* __restrict__ wsu,
               float* __restrict__ pf) {
    __shared__ float s_meta[NSAMP][12];              // int4 o4 | wx wy | cam xyz
    __shared__ float s_cdir[4];
    __shared__ unsigned int h1p[NSAMP * H1S];        // 33,792 B (packed hi|lo)

    const int t = threadIdx.x;
    const int bid = blockIdx.x;
    const int r = bid >> 1, v = bid & 1;
    const int lane = t & 63;
    const int wid = __builtin_amdgcn_readfirstlane(t >> 6);
    const int l15 = lane & 15;
    const int lg  = lane >> 4;
    constexpr float STEP = (ZFAR - ZNEAR) / (NSAMP - 1);

    // ---- projection prep: one thread per sample ----
    if (t < NSAMP) {
        const int p = t;
        const float ox = rayo[r*3+0], oy = rayo[r*3+1], oz = rayo[r*3+2];
        const float dx = rayd[r*3+0], dy = rayd[r*3+1], dz = rayd[r*3+2];
        const float z = ZNEAR + p * STEP;
        const float wxp = ox + z*dx, wyp = oy + z*dy, wzp = oz + z*dz;
        const float* E = einv + v*16;
        const float cx = E[0]*wxp + E[1]*wyp + E[2]*wzp + E[3];
        const float cy = E[4]*wxp + E[5]*wyp + E[6]*wzp + E[7];
        const float cz = E[8]*wxp + E[9]*wyp + E[10]*wzp + E[11];
        const float cw = E[12]*wxp + E[13]*wyp + E[14]*wzp + E[15];
        const float* Km = intr + v*16;
        const float px = Km[0]*cx + Km[1]*cy + Km[2]*cz + Km[3]*cw;
        const float py = Km[4]*cx + Km[5]*cy + Km[6]*cz + Km[7]*cw;
        const float pz = Km[8]*cx + Km[9]*cy + Km[10]*cz + Km[11]*cw;
        const float inv = pz + 1e-8f;
        float fx = px / inv, fy = py / inv;
        fx = fminf(fmaxf(fx, 0.0f), (float)(IMW-1));
        fy = fminf(fmaxf(fy, 0.0f), (float)(IMH-1));
        const int x0 = (int)floorf(fx), y0 = (int)floorf(fy);
        const int x1 = min(x0+1, IMW-1), y1 = min(y0+1, IMH-1);
        const int base = v*IMH*IMW;
        int4 o4; o4.x = (base + y0*IMW + x0) * NFEAT;
                 o4.y = (base + y0*IMW + x1) * NFEAT;
                 o4.z = (base + y1*IMW + x0) * NFEAT;
                 o4.w = (base + y1*IMW + x1) * NFEAT;
        *(int4*)&s_meta[p][0] = o4;
        s_meta[p][4] = fx - (float)x0;
        s_meta[p][5] = fy - (float)y0;
        s_meta[p][6] = cx; s_meta[p][7] = cy; s_meta[p][8] = cz;
        if (t == 0) {
            s_cdir[0] = E[0]*dx + E[1]*dy + E[2]*dz;
            s_cdir[1] = E[4]*dx + E[5]*dy + E[6]*dz;
            s_cdir[2] = E[8]*dx + E[9]*dy + E[10]*dz;
        }
    }
    __syncthreads();

    // ---- per-lane meta for this lane's A-row (sample wid*16 + l15) ----
    const float* mg = s_meta[wid*16 + l15];
    const int4 og = *(const int4*)mg;
    const float wx = mg[4], wy = mg[5];
    const float w00 = (1.f-wx)*(1.f-wy), w01 = wx*(1.f-wy);
    const float w10 = (1.f-wx)*wy,       w11 = wx*wy;
    const float* t00 = feats + og.x;
    const float* t01 = feats + og.y;
    const float* t10 = feats + og.z;
    const float* t11 = feats + og.w;

    float ia = 0.f, ib = 0.f;      // lg==0: img0,img1 ; lg==1: img2
    if (lg < 2) {
        const int i00 = (og.x >> 8) * 3, i01 = (og.y >> 8) * 3;
        const int i10 = (og.z >> 8) * 3, i11 = (og.w >> 8) * 3;
        if (lg == 0) {
            ia = 2.0f*(w00*images[i00+0] + w01*images[i01+0] + w10*images[i10+0] + w11*images[i11+0]) - 1.0f;
            ib = 2.0f*(w00*images[i00+1] + w01*images[i01+1] + w10*images[i10+1] + w11*images[i11+1]) - 1.0f;
        } else {
            ia = 2.0f*(w00*images[i00+2] + w01*images[i01+2] + w10*images[i10+2] + w11*images[i11+2]) - 1.0f;
        }
    }

    auto buildA = [&](int kc, bf16x8& ah, bf16x8& al) {
        float f[8];
        if (kc == 0 && lg == 0) {
            f[0]=mg[6]; f[1]=mg[7]; f[2]=mg[8];
            f[3]=s_cdir[0]; f[4]=s_cdir[1]; f[5]=s_cdir[2];
            f[6]=ia; f[7]=ib;
        } else if (kc == 0 && lg == 1) {
            f[0]=ia;
            #pragma unroll
            for (int i = 1; i < 8; ++i) f[i] = 0.0f;
        } else if (kc == 8 && lg >= 2) {
            #pragma unroll
            for (int i = 0; i < 8; ++i) f[i] = 0.0f;
        } else {
            const int f0 = kc*32 + lg*8 - 16;
            const float4 p00a = *reinterpret_cast<const float4*>(t00 + f0);
            const float4 p00b = *reinterpret_cast<const float4*>(t00 + f0 + 4);
            const float4 p01a = *reinterpret_cast<const float4*>(t01 + f0);
            const float4 p01b = *reinterpret_cast<const float4*>(t01 + f0 + 4);
            const float4 p10a = *reinterpret_cast<const float4*>(t10 + f0);
            const float4 p10b = *reinterpret_cast<const float4*>(t10 + f0 + 4);
            const float4 p11a = *reinterpret_cast<const float4*>(t11 + f0);
            const float4 p11b = *reinterpret_cast<const float4*>(t11 + f0 + 4);
            f[0] = w00*p00a.x + w01*p01a.x + w10*p10a.x + w11*p11a.x;
            f[1] = w00*p00a.y + w01*p01a.y + w10*p10a.y + w11*p11a.y;
            f[2] = w00*p00a.z + w01*p01a.z + w10*p10a.z + w11*p11a.z;
            f[3] = w00*p00a.w + w01*p01a.w + w10*p10a.w + w11*p11a.w;
            f[4] = w00*p00b.x + w01*p01b.x + w10*p10b.x + w11*p11b.x;
            f[5] = w00*p00b.y + w01*p01b.y + w10*p10b.y + w11*p11b.y;
            f[6] = w00*p00b.z + w01*p01b.z + w10*p10b.z + w11*p11b.z;
            f[7] = w00*p00b.w + w01*p01b.w + w10*p10b.w + w11*p11b.w;
        }
        splitpack(f, ah, al);
    };

    // ---- layer 1: kc-outer, acc[8 nt] resident, A(kc+1) prefetched ----
    f32x4 acc[8];
    #pragma unroll
    for (int nt = 0; nt < 8; ++nt) acc[nt] = f32x4{0.f, 0.f, 0.f, 0.f};

    const unsigned short* wb1 = wsu + l15 * KU1 + lg*8;
    bf16x8 ah, al, nh, nl;
    buildA(0, ah, al);
    #pragma unroll
    for (int kc = 0; kc < 9; ++kc) {
        if (kc < 8) buildA(kc+1, nh, nl);
        #pragma unroll
        for (int nt = 0; nt < 8; ++nt) {
            const unsigned short* wp = wb1 + nt * 16 * KU1 + kc*32;
            const bf16x8 bh = *(const bf16x8*)(wp);
            const bf16x8 bl = *(const bf16x8*)(wp + W1LO);
            acc[nt] = __builtin_amdgcn_mfma_f32_16x16x32_bf16(ah, bh, acc[nt], 0, 0, 0);
            acc[nt] = __builtin_amdgcn_mfma_f32_16x16x32_bf16(al, bh, acc[nt], 0, 0, 0);
            acc[nt] = __builtin_amdgcn_mfma_f32_16x16x32_bf16(ah, bl, acc[nt], 0, 0, 0);
        }
        ah = nh; al = nl;
    }
    // bias+relu+pack -> wave-private h1 (no barrier needed: in-order DS per wave)
    const int hrbase = wid*16 + lg*4;
    #pragma unroll
    for (int nt = 0; nt < 8; ++nt) {
        const int ch = nt * 16 + l15;
        const float bb = b1[ch];
        #pragma unroll
        for (int j = 0; j < 4; ++j) {
            const float hv = fmaxf(acc[nt][j] + bb, 0.0f);
            h1p[(hrbase + j) * H1S + ch] = packsplit(hv);
        }
    }

    // ---- layer 2: kc-outer from wave-private packed h1 ----
    const unsigned int* h1row = h1p + (wid*16 + l15) * H1S;
    #pragma unroll
    for (int nt = 0; nt < 8; ++nt) acc[nt] = f32x4{0.f, 0.f, 0.f, 0.f};
    const unsigned short* wb2 = wsu + W2OF + l15 * 128 + lg*8;
    #pragma unroll
    for (int kc = 0; kc < 4; ++kc) {
        const uint4 ua = *reinterpret_cast<const uint4*>(h1row + kc*32 + lg*8);
        const uint4 ub = *reinterpret_cast<const uint4*>(h1row + kc*32 + lg*8 + 4);
        bf16x8 a2h, a2l;
        unpack8(ua, ub, a2h, a2l);
        #pragma unroll
        for (int nt = 0; nt < 8; ++nt) {
            const unsigned short* wp = wb2 + nt * 16 * 128 + kc*32;
            const bf16x8 bh = *(const bf16x8*)(wp);
            const bf16x8 bl = *(const bf16x8*)(wp + W2LO);
            acc[nt] = __builtin_amdgcn_mfma_f32_16x16x32_bf16(a2h, bh, acc[nt], 0, 0, 0);
            acc[nt] = __builtin_amdgcn_mfma_f32_16x16x32_bf16(a2l, bh, acc[nt], 0, 0, 0);
            acc[nt] = __builtin_amdgcn_mfma_f32_16x16x32_bf16(a2h, bl, acc[nt], 0, 0, 0);
        }
    }

    // ---- readout: bias+relu then dot with Wr; reduce over 16 channel lanes ----
    float pr[4][4];
    #pragma unroll
    for (int j = 0; j < 4; ++j)
        #pragma unroll
        for (int q = 0; q < 4; ++q) pr[j][q] = 0.0f;
    #pragma unroll
    for (int nt = 0; nt < 8; ++nt) {
        const int ch = nt * 16 + l15;
        const float bb = b2[ch];
        const float4 wr = *reinterpret_cast<const float4*>(Wr + ch * 4);
        #pragma unroll
        for (int j = 0; j < 4; ++j) {
            const float hv = fmaxf(acc[nt][j] + bb, 0.0f);
            pr[j][0] = fmaf(hv, wr.x, pr[j][0]);
            pr[j][1] = fmaf(hv, wr.y, pr[j][1]);
            pr[j][2] = fmaf(hv, wr.z, pr[j][2]);
            pr[j][3] = fmaf(hv, wr.w, pr[j][3]);
        }
    }
    #pragma unroll
    for (int m = 1; m <= 8; m <<= 1)
        #pragma unroll
        for (int j = 0; j < 4; ++j)
            #pragma unroll
            for (int q = 0; q < 4; ++q)
                pr[j][q] += __shfl_xor(pr[j][q], m, 64);
    if (l15 == 0) {
        #pragma unroll
        for (int j = 0; j < 4; ++j) {
            float4 o;
            o.x = pr[j][0]; o.y = pr[j][1]; o.z = pr[j][2]; o.w = pr[j][3];
            *reinterpret_cast<float4*>(pf + ((size_t)bid * 64 + hrbase + j) * 4) = o;
        }
    }
}

// ---- render: per-ray, lane = sample ----
__global__ __launch_bounds__(64)
void nerf_render(const float* __restrict__ pf,
                 const float* __restrict__ br,
                 float* __restrict__ out) {
    const int r = blockIdx.x;
    const int p = threadIdx.x;
    constexpr float STEP = (ZFAR - ZNEAR) / (NSAMP - 1);
    const float4 a = *reinterpret_cast<const float4*>(pf + ((r*2+0)*NSAMP + p)*4);
    const float4 b = *reinterpret_cast<const float4*>(pf + ((r*2+1)*NSAMP + p)*4);
    const float o0 = 0.5f*(a.x + b.x) + br[0];
    const float o1 = 0.5f*(a.y + b.y) + br[1];
    const float o2 = 0.5f*(a.z + b.z) + br[2];
    const float o3 = 0.5f*(a.w + b.w) + br[3];
    const float c0 = 1.0f/(1.0f + __expf(-o0));
    const float c1 = 1.0f/(1.0f + __expf(-o1));
    const float c2 = 1.0f/(1.0f + __expf(-o2));
    const float dens = fmaxf(o3, 0.0f);
    const float zp = ZNEAR + p * STEP;
    const float zn = ZNEAR + (p+1) * STEP;
    const float dlast = (ZNEAR + 63*STEP) - (ZNEAR + 62*STEP);
    const float dist = (p == NSAMP-1) ? dlast : (zn - zp);
    const float alpha = 1.0f - __expf(-dens*dist);
    float scan = 1.0f - alpha + 1e-10f;
    #pragma unroll
    for (int off = 1; off < 64; off <<= 1) {
        const float vsh = __shfl_up(scan, off, 64);
        if (p >= off) scan *= vsh;
    }
    float trans = __shfl_up(scan, 1, 64);
    if (p == 0) trans = 1.0f;
    const float w = alpha * trans;
    float s0 = w*c0, s1 = w*c1, s2 = w*c2, sd = w*zp;
    #pragma unroll
    for (int m = 32; m > 0; m >>= 1) {
        s0 += __shfl_xor(s0, m, 64);
        s1 += __shfl_xor(s1, m, 64);
        s2 += __shfl_xor(s2, m, 64);
        sd += __shfl_xor(sd, m, 64);
    }
    if (p == 0) {
        out[r*3+0] = s0; out[r*3+1] = s1; out[r*3+2] = s2;
        out[NRAYS*3 + r] = sd;
    }
}

extern "C" void kernel_launch(void* const* d_in, const int* in_sizes, int n_in,
                              void* d_out, int out_size, void* d_ws, size_t ws_size,
                              hipStream_t stream) {
    const float* rayo   = (const float*)d_in[0];
    const float* rayd   = (const float*)d_in[1];
    const float* images = (const float*)d_in[2];
    const float* intr   = (const float*)d_in[3];
    const float* einv   = (const float*)d_in[4];
    const float* feats  = (const float*)d_in[5];
    const float* W1     = (const float*)d_in[6];
    const float* b1     = (const float*)d_in[7];
    const float* W2     = (const float*)d_in[8];
    const float* b2     = (const float*)d_in[9];
    const float* Wr     = (const float*)d_in[10];
    const float* br     = (const float*)d_in[11];
    float* out = (float*)d_out;
    unsigned short* wsu = (unsigned short*)d_ws;                 // W split planes (213 KB)
    float* pf = (float*)((char*)d_ws + 262144);                  // per-(ray,view) partials (1 MB)

    hipLaunchKernelGGL(nerf_prep, dim3(208), dim3(256), 0, stream, W1, W2, wsu);
    hipLaunchKernelGGL(nerf_main, dim3(NRAYS*2), dim3(256), 0, stream,
                       rayo, rayd, images, intr, einv, feats, b1, b2, Wr, wsu, pf);
    hipLaunchKernelGGL(nerf_render, dim3(NRAYS), dim3(64), 0, stream, pf, br, out);
}

// Round 9
// 90.327 us; speedup vs baseline: 1.2174x; 1.2174x over previous
//
#include <hip/hip_runtime.h>
#include <math.h>

#define NRAYS 512
#define NSAMP 64
#define IMH 480
#define IMW 640
#define NFEAT 256
#define ZNEAR 0.7f
#define ZFAR 1.5f
#define KU1 288          // W1 row length (ushorts): k-map 0-8 meta, 9-15 zero, 16-271 feats, 272-287 zero
#define W1LO 36864       // ushort offset of W1 lo plane
#define W2OF 73728       // ushort offset of W2 hi plane
#define W2LO 16384       // relative ushort offset of W2 lo plane
#define H1S 132          // h1 packed row stride (u32): 16B-aligned, 2-way-bank
#define STGS 36          // staging row stride (u32)

typedef __attribute__((ext_vector_type(8))) short bf16x8;
typedef __attribute__((ext_vector_type(4))) float f32x4;

__device__ __forceinline__ unsigned short bf16rne(float f) {
    unsigned int u = __builtin_bit_cast(unsigned int, f);
    unsigned int r = (u + 0x7FFFu + ((u >> 16) & 1u)) >> 16;
    return (unsigned short)r;
}
__device__ __forceinline__ float bf16tof(unsigned short h) {
    unsigned int u = ((unsigned int)h) << 16;
    return __builtin_bit_cast(float, u);
}
__device__ __forceinline__ unsigned int packsplit(float v) {
    const unsigned short h = bf16rne(v);
    const unsigned short l = bf16rne(v - bf16tof(h));
    return (((unsigned int)h) << 16) | (unsigned int)l;
}
__device__ __forceinline__ void unpack8(uint4 a, uint4 b, bf16x8& hi, bf16x8& lo) {
    union { bf16x8 v; unsigned short u[8]; } H, L;
    const unsigned int w[8] = {a.x, a.y, a.z, a.w, b.x, b.y, b.z, b.w};
    #pragma unroll
    for (int i = 0; i < 8; ++i) {
        H.u[i] = (unsigned short)(w[i] >> 16);
        L.u[i] = (unsigned short)(w[i] & 0xFFFFu);
    }
    hi = H.v; lo = L.v;
}

// ---- prep: transpose + bf16-split W1 -> [128][288] (k-map above) and W2 -> [128][128] ----
__global__ __launch_bounds__(256)
void nerf_prep(const float* __restrict__ W1, const float* __restrict__ W2,
               unsigned short* __restrict__ wsu) {
    const int i = blockIdx.x * 256 + threadIdx.x;
    if (i < 36864) {
        const int n = i / KU1, k = i % KU1;
        float val = 0.0f;
        if (k < 9) val = W1[k * 128 + n];
        else if (k >= 16 && k < 272) val = W1[(k - 7) * 128 + n];
        const unsigned short h = bf16rne(val);
        wsu[n * KU1 + k] = h;
        wsu[W1LO + n * KU1 + k] = bf16rne(val - bf16tof(h));
    } else if (i < 53248) {
        const int j = i - 36864;
        const int n = j >> 7, k = j & 127;
        const float val = W2[k * 128 + n];
        const unsigned short h = bf16rne(val);
        wsu[W2OF + n * 128 + k] = h;
        wsu[W2OF + W2LO + n * 128 + k] = bf16rne(val - bf16tof(h));
    }
}

// ---- main: block = (ray,view), 256 thr = 4 waves, wave owns 16 samples.
// Layer 1 is kc-pipelined: per 32-dim chunk {bilerp staged loads -> ds_write ->
// ds_read A-frag -> issue next chunk's loads -> 24-MFMA sweep}. One A-frag +
// acc[8] live -> fits 128 VGPR -> 4 blocks/CU with 36.9 KB LDS (staging buffer
// overlays the wave's own h1 region; wave-private, in-order DS => race-free).
__global__ __launch_bounds__(256, 4)
void nerf_main(const float* __restrict__ rayo,
               const float* __restrict__ rayd,
               const float* __restrict__ images,
               const float* __restrict__ intr,
               const float* __restrict__ einv,
               const float* __restrict__ feats,
               const float* __restrict__ b1,
               const float* __restrict__ b2,
               const float* __restrict__ Wr,
               const unsigned short* __restrict__ wsu,
               float* __restrict__ pf) {
    __shared__ float s_meta[NSAMP][12];              // int4 o4 | wx wy | cam xyz
    __shared__ float s_cdir[4];
    __shared__ unsigned int h1p[NSAMP * H1S];        // 33,792 B; stg overlays per-wave head

    const int t = threadIdx.x;
    const int bid = blockIdx.x;
    const int r = bid >> 1, v = bid & 1;
    const int lane = t & 63;
    const int wid = __builtin_amdgcn_readfirstlane(t >> 6);
    const int l15 = lane & 15;
    const int lg  = lane >> 4;
    const int sq  = lane >> 2;        // staging: sample-within-wave
    const int qq  = lane & 3;         // staging: dim-quad
    constexpr float STEP = (ZFAR - ZNEAR) / (NSAMP - 1);

    // ---- projection prep: one thread per sample ----
    if (t < NSAMP) {
        const int p = t;
        const float ox = rayo[r*3+0], oy = rayo[r*3+1], oz = rayo[r*3+2];
        const float dx = rayd[r*3+0], dy = rayd[r*3+1], dz = rayd[r*3+2];
        const float z = ZNEAR + p * STEP;
        const float wxp = ox + z*dx, wyp = oy + z*dy, wzp = oz + z*dz;
        const float* E = einv + v*16;
        const float cx = E[0]*wxp + E[1]*wyp + E[2]*wzp + E[3];
        const float cy = E[4]*wxp + E[5]*wyp + E[6]*wzp + E[7];
        const float cz = E[8]*wxp + E[9]*wyp + E[10]*wzp + E[11];
        const float cw = E[12]*wxp + E[13]*wyp + E[14]*wzp + E[15];
        const float* Km = intr + v*16;
        const float px = Km[0]*cx + Km[1]*cy + Km[2]*cz + Km[3]*cw;
        const float py = Km[4]*cx + Km[5]*cy + Km[6]*cz + Km[7]*cw;
        const float pz = Km[8]*cx + Km[9]*cy + Km[10]*cz + Km[11]*cw;
        const float inv = pz + 1e-8f;
        float fx = px / inv, fy = py / inv;
        fx = fminf(fmaxf(fx, 0.0f), (float)(IMW-1));
        fy = fminf(fmaxf(fy, 0.0f), (float)(IMH-1));
        const int x0 = (int)floorf(fx), y0 = (int)floorf(fy);
        const int x1 = min(x0+1, IMW-1), y1 = min(y0+1, IMH-1);
        const int base = v*IMH*IMW;
        int4 o4; o4.x = (base + y0*IMW + x0) * NFEAT;
                 o4.y = (base + y0*IMW + x1) * NFEAT;
                 o4.z = (base + y1*IMW + x0) * NFEAT;
                 o4.w = (base + y1*IMW + x1) * NFEAT;
        *(int4*)&s_meta[p][0] = o4;
        s_meta[p][4] = fx - (float)x0;
        s_meta[p][5] = fy - (float)y0;
        s_meta[p][6] = cx; s_meta[p][7] = cy; s_meta[p][8] = cz;
        if (t == 0) {
            s_cdir[0] = E[0]*dx + E[1]*dy + E[2]*dz;
            s_cdir[1] = E[4]*dx + E[5]*dy + E[6]*dz;
            s_cdir[2] = E[8]*dx + E[9]*dy + E[10]*dz;
        }
    }
    __syncthreads();

    // ---- staging meta for this lane's sample (wid*16 + sq) ----
    const float* mg = s_meta[wid*16 + sq];
    const int4 og = *(const int4*)mg;
    const float wx = mg[4], wy = mg[5];
    const float w00 = (1.f-wx)*(1.f-wy), w01 = wx*(1.f-wy);
    const float w10 = (1.f-wx)*wy,       w11 = wx*wy;
    const float* t00 = feats + og.x;
    const float* t01 = feats + og.y;
    const float* t10 = feats + og.z;
    const float* t11 = feats + og.w;

    float ia = 0.f, ib = 0.f;                 // qq==1: img0,img1 ; qq==2: img2
    if (qq == 1 || qq == 2) {
        const int i00 = (og.x >> 8) * 3, i01 = (og.y >> 8) * 3;
        const int i10 = (og.z >> 8) * 3, i11 = (og.w >> 8) * 3;
        if (qq == 1) {
            ia = 2.0f*(w00*images[i00+0] + w01*images[i01+0] + w10*images[i10+0] + w11*images[i11+0]) - 1.0f;
            ib = 2.0f*(w00*images[i00+1] + w01*images[i01+1] + w10*images[i10+1] + w11*images[i11+1]) - 1.0f;
        } else {
            ia = 2.0f*(w00*images[i00+2] + w01*images[i01+2] + w10*images[i10+2] + w11*images[i11+2]) - 1.0f;
        }
    }

    // staging buffer: first 2304 B of this wave's OWN h1 region (rows 16*wid..)
    unsigned int* stg = h1p + wid * (16 * H1S);   // 2112 u32 region, we use 576

    // ---- layer 1: kc-pipelined (stage kc | prefetch kc+1 | 24-MFMA sweep) ----
    f32x4 acc[8];
    #pragma unroll
    for (int nt = 0; nt < 8; ++nt) acc[nt] = f32x4{0.f, 0.f, 0.f, 0.f};
    const unsigned short* wb1 = wsu + l15 * KU1 + lg*8;

    float4 La[4], Lb[4];        // in-flight texel loads: sub0, sub1
    {   // prologue: issue loads for kc=0 (sub0 is meta -> no loads; sub1 = feats qq*4)
        const int f1 = qq*4;
        Lb[0] = *reinterpret_cast<const float4*>(t00 + f1);
        Lb[1] = *reinterpret_cast<const float4*>(t01 + f1);
        Lb[2] = *reinterpret_cast<const float4*>(t10 + f1);
        Lb[3] = *reinterpret_cast<const float4*>(t11 + f1);
    }
    #pragma unroll
    for (int kc = 0; kc < 9; ++kc) {
        // -- bilerp current chunk, write staging --
        float f0[4], f1[4];
        if (kc == 0) {
            if (qq == 0)      { f0[0]=mg[6]; f0[1]=mg[7]; f0[2]=mg[8]; f0[3]=s_cdir[0]; }
            else if (qq == 1) { f0[0]=s_cdir[1]; f0[1]=s_cdir[2]; f0[2]=ia; f0[3]=ib; }
            else if (qq == 2) { f0[0]=ia; f0[1]=0.f; f0[2]=0.f; f0[3]=0.f; }
            else              { f0[0]=0.f; f0[1]=0.f; f0[2]=0.f; f0[3]=0.f; }
        } else {
            f0[0] = w00*La[0].x + w01*La[1].x + w10*La[2].x + w11*La[3].x;
            f0[1] = w00*La[0].y + w01*La[1].y + w10*La[2].y + w11*La[3].y;
            f0[2] = w00*La[0].z + w01*La[1].z + w10*La[2].z + w11*La[3].z;
            f0[3] = w00*La[0].w + w01*La[1].w + w10*La[2].w + w11*La[3].w;
        }
        if (kc == 8) {
            f1[0]=0.f; f1[1]=0.f; f1[2]=0.f; f1[3]=0.f;
        } else {
            f1[0] = w00*Lb[0].x + w01*Lb[1].x + w10*Lb[2].x + w11*Lb[3].x;
            f1[1] = w00*Lb[0].y + w01*Lb[1].y + w10*Lb[2].y + w11*Lb[3].y;
            f1[2] = w00*Lb[0].z + w01*Lb[1].z + w10*Lb[2].z + w11*Lb[3].z;
            f1[3] = w00*Lb[0].w + w01*Lb[1].w + w10*Lb[2].w + w11*Lb[3].w;
        }
        uint4 u0, u1;
        u0.x = packsplit(f0[0]); u0.y = packsplit(f0[1]);
        u0.z = packsplit(f0[2]); u0.w = packsplit(f0[3]);
        u1.x = packsplit(f1[0]); u1.y = packsplit(f1[1]);
        u1.z = packsplit(f1[2]); u1.w = packsplit(f1[3]);
        *reinterpret_cast<uint4*>(stg + sq*STGS + qq*4)      = u0;
        *reinterpret_cast<uint4*>(stg + sq*STGS + 16 + qq*4) = u1;
        // -- transpose read this wave's A-fragment (in-order DS, no barrier) --
        const uint4 ua = *reinterpret_cast<const uint4*>(stg + l15*STGS + lg*8);
        const uint4 ub = *reinterpret_cast<const uint4*>(stg + l15*STGS + lg*8 + 4);
        // -- issue next chunk's loads (hide under MFMA sweep) --
        if (kc < 8) {
            const int n0 = (kc+1)*32 + qq*4 - 16;       // sub0 feats index
            La[0] = *reinterpret_cast<const float4*>(t00 + n0);
            La[1] = *reinterpret_cast<const float4*>(t01 + n0);
            La[2] = *reinterpret_cast<const float4*>(t10 + n0);
            La[3] = *reinterpret_cast<const float4*>(t11 + n0);
            if (kc < 7) {
                const int n1 = n0 + 16;                 // sub1 feats index
                Lb[0] = *reinterpret_cast<const float4*>(t00 + n1);
                Lb[1] = *reinterpret_cast<const float4*>(t01 + n1);
                Lb[2] = *reinterpret_cast<const float4*>(t10 + n1);
                Lb[3] = *reinterpret_cast<const float4*>(t11 + n1);
            }
        }
        bf16x8 ah, al;
        unpack8(ua, ub, ah, al);
        // -- 24-MFMA sweep over the 8 output tiles --
        #pragma unroll
        for (int nt = 0; nt < 8; ++nt) {
            const unsigned short* wp = wb1 + nt * 16 * KU1 + kc*32;
            const bf16x8 bh = *(const bf16x8*)(wp);
            const bf16x8 bl = *(const bf16x8*)(wp + W1LO);
            acc[nt] = __builtin_amdgcn_mfma_f32_16x16x32_bf16(ah, bh, acc[nt], 0, 0, 0);
            acc[nt] = __builtin_amdgcn_mfma_f32_16x16x32_bf16(al, bh, acc[nt], 0, 0, 0);
            acc[nt] = __builtin_amdgcn_mfma_f32_16x16x32_bf16(ah, bl, acc[nt], 0, 0, 0);
        }
    }

    // ---- bias+relu+pack -> wave-private h1 (after all stg reads: safe overlay) ----
    const int hrbase = wid*16 + lg*4;
    #pragma unroll
    for (int nt = 0; nt < 8; ++nt) {
        const int ch = nt * 16 + l15;
        const float bb = b1[ch];
        #pragma unroll
        for (int j = 0; j < 4; ++j) {
            const float hv = fmaxf(acc[nt][j] + bb, 0.0f);
            h1p[(hrbase + j) * H1S + ch] = packsplit(hv);
        }
    }

    // ---- layer 2: A-frags from wave-private packed h1 (no barrier) ----
    const unsigned int* h1row = h1p + (wid*16 + l15) * H1S;
    bf16x8 a2h[4], a2l[4];
    #pragma unroll
    for (int kc = 0; kc < 4; ++kc) {
        const uint4 ua = *reinterpret_cast<const uint4*>(h1row + kc*32 + lg*8);
        const uint4 ub = *reinterpret_cast<const uint4*>(h1row + kc*32 + lg*8 + 4);
        unpack8(ua, ub, a2h[kc], a2l[kc]);
    }
    float pr[4][4];
    #pragma unroll
    for (int j = 0; j < 4; ++j)
        #pragma unroll
        for (int q = 0; q < 4; ++q) pr[j][q] = 0.0f;

    const unsigned short* wb2 = wsu + W2OF + l15 * 128 + lg*8;
    #pragma unroll 2
    for (int nt = 0; nt < 8; ++nt) {
        const unsigned short* wp = wb2 + nt * 16 * 128;
        f32x4 acc2 = {0.f, 0.f, 0.f, 0.f};
        #pragma unroll
        for (int kc = 0; kc < 4; ++kc) {
            const bf16x8 bh = *(const bf16x8*)(wp + kc*32);
            const bf16x8 bl = *(const bf16x8*)(wp + W2LO + kc*32);
            acc2 = __builtin_amdgcn_mfma_f32_16x16x32_bf16(a2h[kc], bh, acc2, 0, 0, 0);
            acc2 = __builtin_amdgcn_mfma_f32_16x16x32_bf16(a2l[kc], bh, acc2, 0, 0, 0);
            acc2 = __builtin_amdgcn_mfma_f32_16x16x32_bf16(a2h[kc], bl, acc2, 0, 0, 0);
        }
        const int ch = nt * 16 + l15;
        const float bb = b2[ch];
        const float4 wr = *reinterpret_cast<const float4*>(Wr + ch * 4);
        #pragma unroll
        for (int j = 0; j < 4; ++j) {
            const float hv = fmaxf(acc2[j] + bb, 0.0f);
            pr[j][0] = fmaf(hv, wr.x, pr[j][0]);
            pr[j][1] = fmaf(hv, wr.y, pr[j][1]);
            pr[j][2] = fmaf(hv, wr.z, pr[j][2]);
            pr[j][3] = fmaf(hv, wr.w, pr[j][3]);
        }
    }
    // reduce across the 16 channel-slice lanes of each lg group
    #pragma unroll
    for (int m = 1; m <= 8; m <<= 1)
        #pragma unroll
        for (int j = 0; j < 4; ++j)
            #pragma unroll
            for (int q = 0; q < 4; ++q)
                pr[j][q] += __shfl_xor(pr[j][q], m, 64);
    if (l15 == 0) {
        #pragma unroll
        for (int j = 0; j < 4; ++j) {
            float4 o;
            o.x = pr[j][0]; o.y = pr[j][1]; o.z = pr[j][2]; o.w = pr[j][3];
            *reinterpret_cast<float4*>(pf + ((size_t)bid * 64 + hrbase + j) * 4) = o;
        }
    }
}

// ---- render: per-ray, lane = sample ----
__global__ __launch_bounds__(64)
void nerf_render(const float* __restrict__ pf,
                 const float* __restrict__ br,
                 float* __restrict__ out) {
    const int r = blockIdx.x;
    const int p = threadIdx.x;
    constexpr float STEP = (ZFAR - ZNEAR) / (NSAMP - 1);
    const float4 a = *reinterpret_cast<const float4*>(pf + ((r*2+0)*NSAMP + p)*4);
    const float4 b = *reinterpret_cast<const float4*>(pf + ((r*2+1)*NSAMP + p)*4);
    const float o0 = 0.5f*(a.x + b.x) + br[0];
    const float o1 = 0.5f*(a.y + b.y) + br[1];
    const float o2 = 0.5f*(a.z + b.z) + br[2];
    const float o3 = 0.5f*(a.w + b.w) + br[3];
    const float c0 = 1.0f/(1.0f + __expf(-o0));
    const float c1 = 1.0f/(1.0f + __expf(-o1));
    const float c2 = 1.0f/(1.0f + __expf(-o2));
    const float dens = fmaxf(o3, 0.0f);
    const float zp = ZNEAR + p * STEP;
    const float zn = ZNEAR + (p+1) * STEP;
    const float dlast = (ZNEAR + 63*STEP) - (ZNEAR + 62*STEP);
    const float dist = (p == NSAMP-1) ? dlast : (zn - zp);
    const float alpha = 1.0f - __expf(-dens*dist);
    float scan = 1.0f - alpha + 1e-10f;
    #pragma unroll
    for (int off = 1; off < 64; off <<= 1) {
        const float vsh = __shfl_up(scan, off, 64);
        if (p >= off) scan *= vsh;
    }
    float trans = __shfl_up(scan, 1, 64);
    if (p == 0) trans = 1.0f;
    const float w = alpha * trans;
    float s0 = w*c0, s1 = w*c1, s2 = w*c2, sd = w*zp;
    #pragma unroll
    for (int m = 32; m > 0; m >>= 1) {
        s0 += __shfl_xor(s0, m, 64);
        s1 += __shfl_xor(s1, m, 64);
        s2 += __shfl_xor(s2, m, 64);
        sd += __shfl_xor(sd, m, 64);
    }
    if (p == 0) {
        out[r*3+0] = s0; out[r*3+1] = s1; out[r*3+2] = s2;
        out[NRAYS*3 + r] = sd;
    }
}

extern "C" void kernel_launch(void* const* d_in, const int* in_sizes, int n_in,
                              void* d_out, int out_size, void* d_ws, size_t ws_size,
                              hipStream_t stream) {
    const float* rayo   = (const float*)d_in[0];
    const float* rayd   = (const float*)d_in[1];
    const float* images = (const float*)d_in[2];
    const float* intr   = (const float*)d_in[3];
    const float* einv   = (const float*)d_in[4];
    const float* feats  = (const float*)d_in[5];
    const float* W1     = (const float*)d_in[6];
    const float* b1     = (const float*)d_in[7];
    const float* W2     = (const float*)d_in[8];
    const float* b2     = (const float*)d_in[9];
    const float* Wr     = (const float*)d_in[10];
    const float* br     = (const float*)d_in[11];
    float* out = (float*)d_out;
    unsigned short* wsu = (unsigned short*)d_ws;                 // W split planes (213 KB)
    float* pf = (float*)((char*)d_ws + 262144);                  // per-(ray,view) partials (1 MB)

    hipLaunchKernelGGL(nerf_prep, dim3(208), dim3(256), 0, stream, W1, W2, wsu);
    hipLaunchKernelGGL(nerf_main, dim3(NRAYS*2), dim3(256), 0, stream,
                       rayo, rayd, images, intr, einv, feats, b1, b2, Wr, wsu, pf);
    hipLaunchKernelGGL(nerf_render, dim3(NRAYS), dim3(64), 0, stream, pf, br, out);
}

// Round 10
// 88.470 us; speedup vs baseline: 1.2429x; 1.0210x over previous
//
#include <hip/hip_runtime.h>
#include <math.h>

#define NRAYS 512
#define NSAMP 64
#define IMH 480
#define IMW 640
#define NFEAT 256
#define ZNEAR 0.7f
#define ZFAR 1.5f
#define KU1 288          // W1 row length (ushorts): k-map 0-8 meta, 9-15 zero, 16-271 feats, 272-287 zero
#define W1LO 36864       // ushort offset of W1 lo plane
#define W2OF 73728       // ushort offset of W2 hi plane
#define W2LO 16384       // relative ushort offset of W2 lo plane
#define H1S 132          // h1 packed row stride (u32): 16B-aligned, 2-way-bank
#define STGS 36          // staging row stride (u32)

typedef __attribute__((ext_vector_type(8))) short bf16x8;
typedef __attribute__((ext_vector_type(4))) float f32x4;

__device__ __forceinline__ unsigned short bf16rne(float f) {
    unsigned int u = __builtin_bit_cast(unsigned int, f);
    unsigned int r = (u + 0x7FFFu + ((u >> 16) & 1u)) >> 16;
    return (unsigned short)r;
}
__device__ __forceinline__ float bf16tof(unsigned short h) {
    unsigned int u = ((unsigned int)h) << 16;
    return __builtin_bit_cast(float, u);
}
__device__ __forceinline__ unsigned int packsplit(float v) {
    const unsigned short h = bf16rne(v);
    const unsigned short l = bf16rne(v - bf16tof(h));
    return (((unsigned int)h) << 16) | (unsigned int)l;
}
__device__ __forceinline__ void unpack8(uint4 a, uint4 b, bf16x8& hi, bf16x8& lo) {
    union { bf16x8 v; unsigned short u[8]; } H, L;
    const unsigned int w[8] = {a.x, a.y, a.z, a.w, b.x, b.y, b.z, b.w};
    #pragma unroll
    for (int i = 0; i < 8; ++i) {
        H.u[i] = (unsigned short)(w[i] >> 16);
        L.u[i] = (unsigned short)(w[i] & 0xFFFFu);
    }
    hi = H.v; lo = L.v;
}

// ---- prep: transpose + bf16-split W1 -> [128][288] (k-map above) and W2 -> [128][128] ----
__global__ __launch_bounds__(256)
void nerf_prep(const float* __restrict__ W1, const float* __restrict__ W2,
               unsigned short* __restrict__ wsu) {
    const int i = blockIdx.x * 256 + threadIdx.x;
    if (i < 36864) {
        const int n = i / KU1, k = i % KU1;
        float val = 0.0f;
        if (k < 9) val = W1[k * 128 + n];
        else if (k >= 16 && k < 272) val = W1[(k - 7) * 128 + n];
        const unsigned short h = bf16rne(val);
        wsu[n * KU1 + k] = h;
        wsu[W1LO + n * KU1 + k] = bf16rne(val - bf16tof(h));
    } else if (i < 53248) {
        const int j = i - 36864;
        const int n = j >> 7, k = j & 127;
        const float val = W2[k * 128 + n];
        const unsigned short h = bf16rne(val);
        wsu[W2OF + n * 128 + k] = h;
        wsu[W2OF + W2LO + n * 128 + k] = bf16rne(val - bf16tof(h));
    }
}

// ---- main: block = ray (512 thr = 8 waves). Waves 0-3: view 0, waves 4-7:
// view 1; each wave owns 16 samples of its view. Per-wave kc-pipelined layer 1
// (stage kc | prefetch kc+1 | 24-MFMA sweep), wave-private h1, layer 2,
// readout partials -> LDS; then ONE barrier and wave 0 renders the ray inline.
__global__ __launch_bounds__(512, 4)
void nerf_main(const float* __restrict__ rayo,
               const float* __restrict__ rayd,
               const float* __restrict__ images,
               const float* __restrict__ intr,
               const float* __restrict__ einv,
               const float* __restrict__ feats,
               const float* __restrict__ b1,
               const float* __restrict__ b2,
               const float* __restrict__ Wr,
               const float* __restrict__ br,
               const unsigned short* __restrict__ wsu,
               float* __restrict__ out) {
    __shared__ float s_meta[2][NSAMP][12];           // int4 o4 | wx wy | cam xyz
    __shared__ float s_cdir[2][4];
    __shared__ unsigned int h1p[2 * NSAMP * H1S];    // 67,584 B; stg overlays per-wave head
    __shared__ float s_part[2][NSAMP][4];            // readout partials per view

    const int t = threadIdx.x;
    const int r = blockIdx.x;
    const int w8 = __builtin_amdgcn_readfirstlane(t >> 6);   // wave 0..7
    const int v = w8 >> 2;                                    // view
    const int wid = w8 & 3;                                   // M-tile within view
    const int lane = t & 63;
    const int l15 = lane & 15;
    const int lg  = lane >> 4;
    const int sq  = lane >> 2;        // staging: sample-within-wave
    const int qq  = lane & 3;         // staging: dim-quad
    constexpr float STEP = (ZFAR - ZNEAR) / (NSAMP - 1);

    // ---- projection prep: threads 0..127 = (view, sample) ----
    if (t < 128) {
        const int vv = t >> 6, p = t & 63;
        const float ox = rayo[r*3+0], oy = rayo[r*3+1], oz = rayo[r*3+2];
        const float dx = rayd[r*3+0], dy = rayd[r*3+1], dz = rayd[r*3+2];
        const float z = ZNEAR + p * STEP;
        const float wxp = ox + z*dx, wyp = oy + z*dy, wzp = oz + z*dz;
        const float* E = einv + vv*16;
        const float cx = E[0]*wxp + E[1]*wyp + E[2]*wzp + E[3];
        const float cy = E[4]*wxp + E[5]*wyp + E[6]*wzp + E[7];
        const float cz = E[8]*wxp + E[9]*wyp + E[10]*wzp + E[11];
        const float cw = E[12]*wxp + E[13]*wyp + E[14]*wzp + E[15];
        const float* Km = intr + vv*16;
        const float px = Km[0]*cx + Km[1]*cy + Km[2]*cz + Km[3]*cw;
        const float py = Km[4]*cx + Km[5]*cy + Km[6]*cz + Km[7]*cw;
        const float pz = Km[8]*cx + Km[9]*cy + Km[10]*cz + Km[11]*cw;
        const float inv = pz + 1e-8f;
        float fx = px / inv, fy = py / inv;
        fx = fminf(fmaxf(fx, 0.0f), (float)(IMW-1));
        fy = fminf(fmaxf(fy, 0.0f), (float)(IMH-1));
        const int x0 = (int)floorf(fx), y0 = (int)floorf(fy);
        const int x1 = min(x0+1, IMW-1), y1 = min(y0+1, IMH-1);
        const int base = vv*IMH*IMW;
        int4 o4; o4.x = (base + y0*IMW + x0) * NFEAT;
                 o4.y = (base + y0*IMW + x1) * NFEAT;
                 o4.z = (base + y1*IMW + x0) * NFEAT;
                 o4.w = (base + y1*IMW + x1) * NFEAT;
        *(int4*)&s_meta[vv][p][0] = o4;
        s_meta[vv][p][4] = fx - (float)x0;
        s_meta[vv][p][5] = fy - (float)y0;
        s_meta[vv][p][6] = cx; s_meta[vv][p][7] = cy; s_meta[vv][p][8] = cz;
        if (p == 0) {
            s_cdir[vv][0] = E[0]*dx + E[1]*dy + E[2]*dz;
            s_cdir[vv][1] = E[4]*dx + E[5]*dy + E[6]*dz;
            s_cdir[vv][2] = E[8]*dx + E[9]*dy + E[10]*dz;
        }
    }
    __syncthreads();

    // ---- staging meta for this lane's sample (view v, sample wid*16+sq) ----
    const float* mg = s_meta[v][wid*16 + sq];
    const int4 og = *(const int4*)mg;
    const float wx = mg[4], wy = mg[5];
    const float w00 = (1.f-wx)*(1.f-wy), w01 = wx*(1.f-wy);
    const float w10 = (1.f-wx)*wy,       w11 = wx*wy;
    const float* t00 = feats + og.x;
    const float* t01 = feats + og.y;
    const float* t10 = feats + og.z;
    const float* t11 = feats + og.w;

    float ia = 0.f, ib = 0.f;                 // qq==1: img0,img1 ; qq==2: img2
    if (qq == 1 || qq == 2) {
        const int i00 = (og.x >> 8) * 3, i01 = (og.y >> 8) * 3;
        const int i10 = (og.z >> 8) * 3, i11 = (og.w >> 8) * 3;
        if (qq == 1) {
            ia = 2.0f*(w00*images[i00+0] + w01*images[i01+0] + w10*images[i10+0] + w11*images[i11+0]) - 1.0f;
            ib = 2.0f*(w00*images[i00+1] + w01*images[i01+1] + w10*images[i10+1] + w11*images[i11+1]) - 1.0f;
        } else {
            ia = 2.0f*(w00*images[i00+2] + w01*images[i01+2] + w10*images[i10+2] + w11*images[i11+2]) - 1.0f;
        }
    }

    // staging buffer: first 2304 B of this wave's OWN h1 region (wave-private)
    unsigned int* stg = h1p + w8 * (16 * H1S);

    // ---- layer 1: kc-pipelined (stage kc | prefetch kc+1 | 24-MFMA sweep) ----
    f32x4 acc[8];
    #pragma unroll
    for (int nt = 0; nt < 8; ++nt) acc[nt] = f32x4{0.f, 0.f, 0.f, 0.f};
    const unsigned short* wb1 = wsu + l15 * KU1 + lg*8;

    float4 La[4], Lb[4];        // in-flight texel loads: sub0, sub1
    {   // prologue: kc=0 sub0 is meta -> no loads; sub1 = feats qq*4
        const int f1 = qq*4;
        Lb[0] = *reinterpret_cast<const float4*>(t00 + f1);
        Lb[1] = *reinterpret_cast<const float4*>(t01 + f1);
        Lb[2] = *reinterpret_cast<const float4*>(t10 + f1);
        Lb[3] = *reinterpret_cast<const float4*>(t11 + f1);
    }
    #pragma unroll
    for (int kc = 0; kc < 9; ++kc) {
        // -- bilerp current chunk, write staging --
        float f0[4], f1[4];
        if (kc == 0) {
            if (qq == 0)      { f0[0]=mg[6]; f0[1]=mg[7]; f0[2]=mg[8]; f0[3]=s_cdir[v][0]; }
            else if (qq == 1) { f0[0]=s_cdir[v][1]; f0[1]=s_cdir[v][2]; f0[2]=ia; f0[3]=ib; }
            else if (qq == 2) { f0[0]=ia; f0[1]=0.f; f0[2]=0.f; f0[3]=0.f; }
            else              { f0[0]=0.f; f0[1]=0.f; f0[2]=0.f; f0[3]=0.f; }
        } else {
            f0[0] = w00*La[0].x + w01*La[1].x + w10*La[2].x + w11*La[3].x;
            f0[1] = w00*La[0].y + w01*La[1].y + w10*La[2].y + w11*La[3].y;
            f0[2] = w00*La[0].z + w01*La[1].z + w10*La[2].z + w11*La[3].z;
            f0[3] = w00*La[0].w + w01*La[1].w + w10*La[2].w + w11*La[3].w;
        }
        if (kc == 8) {
            f1[0]=0.f; f1[1]=0.f; f1[2]=0.f; f1[3]=0.f;
        } else {
            f1[0] = w00*Lb[0].x + w01*Lb[1].x + w10*Lb[2].x + w11*Lb[3].x;
            f1[1] = w00*Lb[0].y + w01*Lb[1].y + w10*Lb[2].y + w11*Lb[3].y;
            f1[2] = w00*Lb[0].z + w01*Lb[1].z + w10*Lb[2].z + w11*Lb[3].z;
            f1[3] = w00*Lb[0].w + w01*Lb[1].w + w10*Lb[2].w + w11*Lb[3].w;
        }
        uint4 u0, u1;
        u0.x = packsplit(f0[0]); u0.y = packsplit(f0[1]);
        u0.z = packsplit(f0[2]); u0.w = packsplit(f0[3]);
        u1.x = packsplit(f1[0]); u1.y = packsplit(f1[1]);
        u1.z = packsplit(f1[2]); u1.w = packsplit(f1[3]);
        *reinterpret_cast<uint4*>(stg + sq*STGS + qq*4)      = u0;
        *reinterpret_cast<uint4*>(stg + sq*STGS + 16 + qq*4) = u1;
        // -- transpose read this wave's A-fragment (in-order DS, no barrier) --
        const uint4 ua = *reinterpret_cast<const uint4*>(stg + l15*STGS + lg*8);
        const uint4 ub = *reinterpret_cast<const uint4*>(stg + l15*STGS + lg*8 + 4);
        // -- issue next chunk's loads (hide under MFMA sweep) --
        if (kc < 8) {
            const int n0 = (kc+1)*32 + qq*4 - 16;       // sub0 feats index
            La[0] = *reinterpret_cast<const float4*>(t00 + n0);
            La[1] = *reinterpret_cast<const float4*>(t01 + n0);
            La[2] = *reinterpret_cast<const float4*>(t10 + n0);
            La[3] = *reinterpret_cast<const float4*>(t11 + n0);
            if (kc < 7) {
                const int n1 = n0 + 16;                 // sub1 feats index
                Lb[0] = *reinterpret_cast<const float4*>(t00 + n1);
                Lb[1] = *reinterpret_cast<const float4*>(t01 + n1);
                Lb[2] = *reinterpret_cast<const float4*>(t10 + n1);
                Lb[3] = *reinterpret_cast<const float4*>(t11 + n1);
            }
        }
        bf16x8 ah, al;
        unpack8(ua, ub, ah, al);
        // -- 24-MFMA sweep over the 8 output tiles --
        #pragma unroll
        for (int nt = 0; nt < 8; ++nt) {
            const unsigned short* wp = wb1 + nt * 16 * KU1 + kc*32;
            const bf16x8 bh = *(const bf16x8*)(wp);
            const bf16x8 bl = *(const bf16x8*)(wp + W1LO);
            acc[nt] = __builtin_amdgcn_mfma_f32_16x16x32_bf16(ah, bh, acc[nt], 0, 0, 0);
            acc[nt] = __builtin_amdgcn_mfma_f32_16x16x32_bf16(al, bh, acc[nt], 0, 0, 0);
            acc[nt] = __builtin_amdgcn_mfma_f32_16x16x32_bf16(ah, bl, acc[nt], 0, 0, 0);
        }
    }

    // ---- bias+relu+pack -> wave-private h1 (after all stg reads: safe overlay) ----
    const int hrow0 = v*NSAMP + wid*16;                 // this wave's h1 row base
    const int hrbase = wid*16 + lg*4;                   // sample-row base within view
    #pragma unroll
    for (int nt = 0; nt < 8; ++nt) {
        const int ch = nt * 16 + l15;
        const float bb = b1[ch];
        #pragma unroll
        for (int j = 0; j < 4; ++j) {
            const float hv = fmaxf(acc[nt][j] + bb, 0.0f);
            h1p[(hrow0 + lg*4 + j) * H1S + ch] = packsplit(hv);
        }
    }

    // ---- layer 2: A-frags from wave-private packed h1 (no barrier) ----
    const unsigned int* h1row = h1p + (hrow0 + l15) * H1S;
    bf16x8 a2h[4], a2l[4];
    #pragma unroll
    for (int kc = 0; kc < 4; ++kc) {
        const uint4 ua = *reinterpret_cast<const uint4*>(h1row + kc*32 + lg*8);
        const uint4 ub = *reinterpret_cast<const uint4*>(h1row + kc*32 + lg*8 + 4);
        unpack8(ua, ub, a2h[kc], a2l[kc]);
    }
    float pr[4][4];
    #pragma unroll
    for (int j = 0; j < 4; ++j)
        #pragma unroll
        for (int q = 0; q < 4; ++q) pr[j][q] = 0.0f;

    const unsigned short* wb2 = wsu + W2OF + l15 * 128 + lg*8;
    #pragma unroll 2
    for (int nt = 0; nt < 8; ++nt) {
        const unsigned short* wp = wb2 + nt * 16 * 128;
        f32x4 acc2 = {0.f, 0.f, 0.f, 0.f};
        #pragma unroll
        for (int kc = 0; kc < 4; ++kc) {
            const bf16x8 bh = *(const bf16x8*)(wp + kc*32);
            const bf16x8 bl = *(const bf16x8*)(wp + W2LO + kc*32);
            acc2 = __builtin_amdgcn_mfma_f32_16x16x32_bf16(a2h[kc], bh, acc2, 0, 0, 0);
            acc2 = __builtin_amdgcn_mfma_f32_16x16x32_bf16(a2l[kc], bh, acc2, 0, 0, 0);
            acc2 = __builtin_amdgcn_mfma_f32_16x16x32_bf16(a2h[kc], bl, acc2, 0, 0, 0);
        }
        const int ch = nt * 16 + l15;
        const float bb = b2[ch];
        const float4 wr = *reinterpret_cast<const float4*>(Wr + ch * 4);
        #pragma unroll
        for (int j = 0; j < 4; ++j) {
            const float hv = fmaxf(acc2[j] + bb, 0.0f);
            pr[j][0] = fmaf(hv, wr.x, pr[j][0]);
            pr[j][1] = fmaf(hv, wr.y, pr[j][1]);
            pr[j][2] = fmaf(hv, wr.z, pr[j][2]);
            pr[j][3] = fmaf(hv, wr.w, pr[j][3]);
        }
    }
    // reduce across the 16 channel-slice lanes of each lg group
    #pragma unroll
    for (int m = 1; m <= 8; m <<= 1)
        #pragma unroll
        for (int j = 0; j < 4; ++j)
            #pragma unroll
            for (int q = 0; q < 4; ++q)
                pr[j][q] += __shfl_xor(pr[j][q], m, 64);
    if (l15 == 0) {
        #pragma unroll
        for (int j = 0; j < 4; ++j) {
            float4 o;
            o.x = pr[j][0]; o.y = pr[j][1]; o.z = pr[j][2]; o.w = pr[j][3];
            *reinterpret_cast<float4*>(&s_part[v][hrbase + j][0]) = o;
        }
    }
    __syncthreads();

    // ---- render inline: wave 0, lane = sample ----
    if (t < NSAMP) {
        const int p = t;
        const float o0 = 0.5f*(s_part[0][p][0] + s_part[1][p][0]) + br[0];
        const float o1 = 0.5f*(s_part[0][p][1] + s_part[1][p][1]) + br[1];
        const float o2 = 0.5f*(s_part[0][p][2] + s_part[1][p][2]) + br[2];
        const float o3 = 0.5f*(s_part[0][p][3] + s_part[1][p][3]) + br[3];
        const float c0 = 1.0f/(1.0f + __expf(-o0));
        const float c1 = 1.0f/(1.0f + __expf(-o1));
        const float c2 = 1.0f/(1.0f + __expf(-o2));
        const float dens = fmaxf(o3, 0.0f);
        const float zp = ZNEAR + p * STEP;
        const float zn = ZNEAR + (p+1) * STEP;
        const float dlast = (ZNEAR + 63*STEP) - (ZNEAR + 62*STEP);
        const float dist = (p == NSAMP-1) ? dlast : (zn - zp);
        const float alpha = 1.0f - __expf(-dens*dist);
        float scan = 1.0f - alpha + 1e-10f;              // inclusive cumprod
        #pragma unroll
        for (int off = 1; off < 64; off <<= 1) {
            const float vsh = __shfl_up(scan, off, 64);
            if (p >= off) scan *= vsh;
        }
        float trans = __shfl_up(scan, 1, 64);            // exclusive
        if (p == 0) trans = 1.0f;
        const float w = alpha * trans;
        float s0 = w*c0, s1 = w*c1, s2 = w*c2, sd = w*zp;
        #pragma unroll
        for (int m = 32; m > 0; m >>= 1) {
            s0 += __shfl_xor(s0, m, 64);
            s1 += __shfl_xor(s1, m, 64);
            s2 += __shfl_xor(s2, m, 64);
            sd += __shfl_xor(sd, m, 64);
        }
        if (p == 0) {
            out[r*3+0] = s0; out[r*3+1] = s1; out[r*3+2] = s2;
            out[NRAYS*3 + r] = sd;
        }
    }
}

extern "C" void kernel_launch(void* const* d_in, const int* in_sizes, int n_in,
                              void* d_out, int out_size, void* d_ws, size_t ws_size,
                              hipStream_t stream) {
    const float* rayo   = (const float*)d_in[0];
    const float* rayd   = (const float*)d_in[1];
    const float* images = (const float*)d_in[2];
    const float* intr   = (const float*)d_in[3];
    const float* einv   = (const float*)d_in[4];
    const float* feats  = (const float*)d_in[5];
    const float* W1     = (const float*)d_in[6];
    const float* b1     = (const float*)d_in[7];
    const float* W2     = (const float*)d_in[8];
    const float* b2     = (const float*)d_in[9];
    const float* Wr     = (const float*)d_in[10];
    const float* br     = (const float*)d_in[11];
    float* out = (float*)d_out;
    unsigned short* wsu = (unsigned short*)d_ws;                 // W split planes (213 KB)

    hipLaunchKernelGGL(nerf_prep, dim3(208), dim3(256), 0, stream, W1, W2, wsu);
    hipLaunchKernelGGL(nerf_main, dim3(NRAYS), dim3(512), 0, stream,
                       rayo, rayd, images, intr, einv, feats, b1, b2, Wr, br, wsu, out);
}

// Round 11
// 53.969 us; speedup vs baseline: 2.0375x; 1.6393x over previous
//
#include <hip/hip_runtime.h>
#include <math.h>

#define NRAYS 512
#define NSAMP 64
#define IMH 480
#define IMW 640
#define NFEAT 256
#define ZNEAR 0.7f
#define ZFAR 1.5f
#define KU1 288          // W1 row length (ushorts): k-map 0-8 meta, 9-15 zero, 16-271 feats, 272-287 zero
#define W1LO 36864       // ushort offset of W1 lo plane
#define W2OF 73728       // ushort offset of W2 hi plane
#define W2LO 16384       // relative ushort offset of W2 lo plane
#define H1S 132          // h1 packed row stride (u32): 16B-aligned, 2-way-bank
#define STGS 36          // x staging row stride (u32)
#define WROW 40          // LDS W-chunk row stride (ushorts, 80B: 16B-aligned, 2-way-bank)
#define WPLANE 5120      // 128*WROW: lo-plane offset within a chunk buffer (ushorts)
#define WBUF 10240       // one chunk buffer = 2 planes (ushorts)

typedef __attribute__((ext_vector_type(8))) short bf16x8;
typedef __attribute__((ext_vector_type(4))) float f32x4;

__device__ __forceinline__ unsigned short bf16rne(float f) {
    unsigned int u = __builtin_bit_cast(unsigned int, f);
    unsigned int r = (u + 0x7FFFu + ((u >> 16) & 1u)) >> 16;
    return (unsigned short)r;
}
__device__ __forceinline__ float bf16tof(unsigned short h) {
    unsigned int u = ((unsigned int)h) << 16;
    return __builtin_bit_cast(float, u);
}
__device__ __forceinline__ unsigned int packsplit(float v) {
    const unsigned short h = bf16rne(v);
    const unsigned short l = bf16rne(v - bf16tof(h));
    return (((unsigned int)h) << 16) | (unsigned int)l;
}
__device__ __forceinline__ void unpack8(uint4 a, uint4 b, bf16x8& hi, bf16x8& lo) {
    union { bf16x8 v; unsigned short u[8]; } H, L;
    const unsigned int w[8] = {a.x, a.y, a.z, a.w, b.x, b.y, b.z, b.w};
    #pragma unroll
    for (int i = 0; i < 8; ++i) {
        H.u[i] = (unsigned short)(w[i] >> 16);
        L.u[i] = (unsigned short)(w[i] & 0xFFFFu);
    }
    hi = H.v; lo = L.v;
}

// ---- prep: transpose + bf16-split W1 -> [128][288] (k-map above) and W2 -> [128][128] ----
__global__ __launch_bounds__(256)
void nerf_prep(const float* __restrict__ W1, const float* __restrict__ W2,
               unsigned short* __restrict__ wsu) {
    const int i = blockIdx.x * 256 + threadIdx.x;
    if (i < 36864) {
        const int n = i / KU1, k = i % KU1;
        float val = 0.0f;
        if (k < 9) val = W1[k * 128 + n];
        else if (k >= 16 && k < 272) val = W1[(k - 7) * 128 + n];
        const unsigned short h = bf16rne(val);
        wsu[n * KU1 + k] = h;
        wsu[W1LO + n * KU1 + k] = bf16rne(val - bf16tof(h));
    } else if (i < 53248) {
        const int j = i - 36864;
        const int n = j >> 7, k = j & 127;
        const float val = W2[k * 128 + n];
        const unsigned short h = bf16rne(val);
        wsu[W2OF + n * 128 + k] = h;
        wsu[W2OF + W2LO + n * 128 + k] = bf16rne(val - bf16tof(h));
    }
}

// ---- main: block = ray (512 thr = 8 waves). Waves 0-3: view 0, waves 4-7:
// view 1; each wave owns 16 samples. W streamed global->LDS in 32-dim chunks,
// double-buffered, ONE barrier per chunk (all 8 waves share each chunk: 8x
// less L2 traffic than per-wave streaming). x staged per-wave (transpose via
// own-h1-overlay LDS), texels prefetched one chunk ahead. 3-pass split-bf16
// MFMA. Render fused at the end.
__global__ __launch_bounds__(512, 2)
void nerf_main(const float* __restrict__ rayo,
               const float* __restrict__ rayd,
               const float* __restrict__ images,
               const float* __restrict__ intr,
               const float* __restrict__ einv,
               const float* __restrict__ feats,
               const float* __restrict__ b1,
               const float* __restrict__ b2,
               const float* __restrict__ Wr,
               const float* __restrict__ br,
               const unsigned short* __restrict__ wsu,
               float* __restrict__ out) {
    __shared__ float s_meta[2][NSAMP][12];           // int4 o4 | wx wy | cam xyz
    __shared__ float s_cdir[2][4];
    __shared__ unsigned int h1p[2 * NSAMP * H1S];    // 67,584 B; x-stg overlays per-wave head
    __shared__ float s_part[2][NSAMP][4];            // readout partials per view
    __shared__ unsigned short ldsW[2 * WBUF];        // 40,960 B: W-chunk double buffer

    const int t = threadIdx.x;
    const int r = blockIdx.x;
    const int w8 = __builtin_amdgcn_readfirstlane(t >> 6);   // wave 0..7
    const int v = w8 >> 2;                                    // view
    const int wid = w8 & 3;                                   // M-tile within view
    const int lane = t & 63;
    const int l15 = lane & 15;
    const int lg  = lane >> 4;
    const int sq  = lane >> 2;        // x staging: sample-within-wave
    const int qq  = lane & 3;         // x staging: dim-quad
    constexpr float STEP = (ZFAR - ZNEAR) / (NSAMP - 1);

    // W-chunk staging role for this thread: plane p, row n, col-half h
    const int sp = t >> 8;            // 0 = hi plane, 1 = lo plane
    const int sn = (t & 255) >> 1;    // row 0..127
    const int sh = (t & 1) * 16;      // col half (ushorts)

    // ---- issue W1 chunk 0 loads immediately (latency hides under meta prep) ----
    uint4 wa = *reinterpret_cast<const uint4*>(wsu + sp*W1LO + sn*KU1 + sh);
    uint4 wb = *reinterpret_cast<const uint4*>(wsu + sp*W1LO + sn*KU1 + sh + 8);

    // ---- projection prep: threads 0..127 = (view, sample) ----
    if (t < 128) {
        const int vv = t >> 6, p = t & 63;
        const float ox = rayo[r*3+0], oy = rayo[r*3+1], oz = rayo[r*3+2];
        const float dx = rayd[r*3+0], dy = rayd[r*3+1], dz = rayd[r*3+2];
        const float z = ZNEAR + p * STEP;
        const float wxp = ox + z*dx, wyp = oy + z*dy, wzp = oz + z*dz;
        const float* E = einv + vv*16;
        const float cx = E[0]*wxp + E[1]*wyp + E[2]*wzp + E[3];
        const float cy = E[4]*wxp + E[5]*wyp + E[6]*wzp + E[7];
        const float cz = E[8]*wxp + E[9]*wyp + E[10]*wzp + E[11];
        const float cw = E[12]*wxp + E[13]*wyp + E[14]*wzp + E[15];
        const float* Km = intr + vv*16;
        const float px = Km[0]*cx + Km[1]*cy + Km[2]*cz + Km[3]*cw;
        const float py = Km[4]*cx + Km[5]*cy + Km[6]*cz + Km[7]*cw;
        const float pz = Km[8]*cx + Km[9]*cy + Km[10]*cz + Km[11]*cw;
        const float inv = pz + 1e-8f;
        float fx = px / inv, fy = py / inv;
        fx = fminf(fmaxf(fx, 0.0f), (float)(IMW-1));
        fy = fminf(fmaxf(fy, 0.0f), (float)(IMH-1));
        const int x0 = (int)floorf(fx), y0 = (int)floorf(fy);
        const int x1 = min(x0+1, IMW-1), y1 = min(y0+1, IMH-1);
        const int base = vv*IMH*IMW;
        int4 o4; o4.x = (base + y0*IMW + x0) * NFEAT;
                 o4.y = (base + y0*IMW + x1) * NFEAT;
                 o4.z = (base + y1*IMW + x0) * NFEAT;
                 o4.w = (base + y1*IMW + x1) * NFEAT;
        *(int4*)&s_meta[vv][p][0] = o4;
        s_meta[vv][p][4] = fx - (float)x0;
        s_meta[vv][p][5] = fy - (float)y0;
        s_meta[vv][p][6] = cx; s_meta[vv][p][7] = cy; s_meta[vv][p][8] = cz;
        if (p == 0) {
            s_cdir[vv][0] = E[0]*dx + E[1]*dy + E[2]*dz;
            s_cdir[vv][1] = E[4]*dx + E[5]*dy + E[6]*dz;
            s_cdir[vv][2] = E[8]*dx + E[9]*dy + E[10]*dz;
        }
    }
    // write W1 chunk 0 into buffer 0 (covered by the same barrier as meta)
    {
        unsigned short* d = ldsW + sp*WPLANE + sn*WROW + sh;
        *reinterpret_cast<uint4*>(d)     = wa;
        *reinterpret_cast<uint4*>(d + 8) = wb;
    }
    __syncthreads();

    // ---- staging meta for this lane's sample (view v, sample wid*16+sq) ----
    const float* mg = s_meta[v][wid*16 + sq];
    const int4 og = *(const int4*)mg;
    const float wx = mg[4], wy = mg[5];
    const float w00 = (1.f-wx)*(1.f-wy), w01 = wx*(1.f-wy);
    const float w10 = (1.f-wx)*wy,       w11 = wx*wy;
    const float* t00 = feats + og.x;
    const float* t01 = feats + og.y;
    const float* t10 = feats + og.z;
    const float* t11 = feats + og.w;

    float ia = 0.f, ib = 0.f;                 // qq==1: img0,img1 ; qq==2: img2
    if (qq == 1 || qq == 2) {
        const int i00 = (og.x >> 8) * 3, i01 = (og.y >> 8) * 3;
        const int i10 = (og.z >> 8) * 3, i11 = (og.w >> 8) * 3;
        if (qq == 1) {
            ia = 2.0f*(w00*images[i00+0] + w01*images[i01+0] + w10*images[i10+0] + w11*images[i11+0]) - 1.0f;
            ib = 2.0f*(w00*images[i00+1] + w01*images[i01+1] + w10*images[i10+1] + w11*images[i11+1]) - 1.0f;
        } else {
            ia = 2.0f*(w00*images[i00+2] + w01*images[i01+2] + w10*images[i10+2] + w11*images[i11+2]) - 1.0f;
        }
    }

    // x staging buffer: head of this wave's OWN h1 region (wave-private)
    unsigned int* stg = h1p + w8 * (16 * H1S);

    // ---- layer 1: kc loop, W double-buffered in LDS, texels prefetched ----
    f32x4 acc[8];
    #pragma unroll
    for (int nt = 0; nt < 8; ++nt) acc[nt] = f32x4{0.f, 0.f, 0.f, 0.f};

    float4 La[4], Lb[4];        // in-flight texel loads: sub0, sub1
    {   // prologue: kc=0 sub0 is meta -> no loads; sub1 = feats qq*4
        const int f1 = qq*4;
        Lb[0] = *reinterpret_cast<const float4*>(t00 + f1);
        Lb[1] = *reinterpret_cast<const float4*>(t01 + f1);
        Lb[2] = *reinterpret_cast<const float4*>(t10 + f1);
        Lb[3] = *reinterpret_cast<const float4*>(t11 + f1);
    }
    int cur = 0;
    #pragma unroll
    for (int kc = 0; kc < 9; ++kc) {
        // -- issue next W-chunk global loads (W1 kc+1, or W2 chunk 0 at kc==8) --
        {
            const unsigned short* s = (kc < 8)
                ? (wsu + sp*W1LO + sn*KU1 + (kc+1)*32 + sh)
                : (wsu + W2OF + sp*W2LO + sn*128 + sh);
            wa = *reinterpret_cast<const uint4*>(s);
            wb = *reinterpret_cast<const uint4*>(s + 8);
        }
        // -- bilerp current chunk, write x staging --
        float f0[4], f1[4];
        if (kc == 0) {
            if (qq == 0)      { f0[0]=mg[6]; f0[1]=mg[7]; f0[2]=mg[8]; f0[3]=s_cdir[v][0]; }
            else if (qq == 1) { f0[0]=s_cdir[v][1]; f0[1]=s_cdir[v][2]; f0[2]=ia; f0[3]=ib; }
            else if (qq == 2) { f0[0]=ia; f0[1]=0.f; f0[2]=0.f; f0[3]=0.f; }
            else              { f0[0]=0.f; f0[1]=0.f; f0[2]=0.f; f0[3]=0.f; }
        } else {
            f0[0] = w00*La[0].x + w01*La[1].x + w10*La[2].x + w11*La[3].x;
            f0[1] = w00*La[0].y + w01*La[1].y + w10*La[2].y + w11*La[3].y;
            f0[2] = w00*La[0].z + w01*La[1].z + w10*La[2].z + w11*La[3].z;
            f0[3] = w00*La[0].w + w01*La[1].w + w10*La[2].w + w11*La[3].w;
        }
        if (kc == 8) {
            f1[0]=0.f; f1[1]=0.f; f1[2]=0.f; f1[3]=0.f;
        } else {
            f1[0] = w00*Lb[0].x + w01*Lb[1].x + w10*Lb[2].x + w11*Lb[3].x;
            f1[1] = w00*Lb[0].y + w01*Lb[1].y + w10*Lb[2].y + w11*Lb[3].y;
            f1[2] = w00*Lb[0].z + w01*Lb[1].z + w10*Lb[2].z + w11*Lb[3].z;
            f1[3] = w00*Lb[0].w + w01*Lb[1].w + w10*Lb[2].w + w11*Lb[3].w;
        }
        uint4 u0, u1;
        u0.x = packsplit(f0[0]); u0.y = packsplit(f0[1]);
        u0.z = packsplit(f0[2]); u0.w = packsplit(f0[3]);
        u1.x = packsplit(f1[0]); u1.y = packsplit(f1[1]);
        u1.z = packsplit(f1[2]); u1.w = packsplit(f1[3]);
        *reinterpret_cast<uint4*>(stg + sq*STGS + qq*4)      = u0;
        *reinterpret_cast<uint4*>(stg + sq*STGS + 16 + qq*4) = u1;
        // -- transpose read this wave's A-fragment (in-order DS, wave-private) --
        const uint4 ua = *reinterpret_cast<const uint4*>(stg + l15*STGS + lg*8);
        const uint4 ub = *reinterpret_cast<const uint4*>(stg + l15*STGS + lg*8 + 4);
        // -- issue next chunk's texel loads (hide under MFMA sweep) --
        if (kc < 8) {
            const int n0 = (kc+1)*32 + qq*4 - 16;
            La[0] = *reinterpret_cast<const float4*>(t00 + n0);
            La[1] = *reinterpret_cast<const float4*>(t01 + n0);
            La[2] = *reinterpret_cast<const float4*>(t10 + n0);
            La[3] = *reinterpret_cast<const float4*>(t11 + n0);
            if (kc < 7) {
                const int n1 = n0 + 16;
                Lb[0] = *reinterpret_cast<const float4*>(t00 + n1);
                Lb[1] = *reinterpret_cast<const float4*>(t01 + n1);
                Lb[2] = *reinterpret_cast<const float4*>(t10 + n1);
                Lb[3] = *reinterpret_cast<const float4*>(t11 + n1);
            }
        }
        bf16x8 ah, al;
        unpack8(ua, ub, ah, al);
        // -- 24-MFMA sweep, B-operands from LDS chunk (2-way-bank ds_read_b128) --
        {
            const unsigned short* wL = ldsW + cur*WBUF + l15*WROW + lg*8;
            #pragma unroll
            for (int nt = 0; nt < 8; ++nt) {
                const bf16x8 bh = *(const bf16x8*)(wL + nt*16*WROW);
                const bf16x8 bl = *(const bf16x8*)(wL + WPLANE + nt*16*WROW);
                acc[nt] = __builtin_amdgcn_mfma_f32_16x16x32_bf16(ah, bh, acc[nt], 0, 0, 0);
                acc[nt] = __builtin_amdgcn_mfma_f32_16x16x32_bf16(al, bh, acc[nt], 0, 0, 0);
                acc[nt] = __builtin_amdgcn_mfma_f32_16x16x32_bf16(ah, bl, acc[nt], 0, 0, 0);
            }
        }
        // -- write staged next W-chunk to the alternate buffer, flip --
        {
            unsigned short* d = ldsW + (cur^1)*WBUF + sp*WPLANE + sn*WROW + sh;
            *reinterpret_cast<uint4*>(d)     = wa;
            *reinterpret_cast<uint4*>(d + 8) = wb;
        }
        __syncthreads();
        cur ^= 1;
    }

    // ---- bias+relu+pack -> wave-private h1 ----
    const int hrow0 = v*NSAMP + wid*16;
    const int hrbase = wid*16 + lg*4;
    #pragma unroll
    for (int nt = 0; nt < 8; ++nt) {
        const int ch = nt * 16 + l15;
        const float bb = b1[ch];
        #pragma unroll
        for (int j = 0; j < 4; ++j) {
            const float hv = fmaxf(acc[nt][j] + bb, 0.0f);
            h1p[(hrow0 + lg*4 + j) * H1S + ch] = packsplit(hv);
        }
    }

    // ---- layer 2: kc-outer, W2 chunks double-buffered in LDS ----
    const unsigned int* h1row = h1p + (hrow0 + l15) * H1S;
    #pragma unroll
    for (int nt = 0; nt < 8; ++nt) acc[nt] = f32x4{0.f, 0.f, 0.f, 0.f};
    #pragma unroll
    for (int kc = 0; kc < 4; ++kc) {
        if (kc < 3) {
            const unsigned short* s = wsu + W2OF + sp*W2LO + sn*128 + (kc+1)*32 + sh;
            wa = *reinterpret_cast<const uint4*>(s);
            wb = *reinterpret_cast<const uint4*>(s + 8);
        }
        const uint4 ua = *reinterpret_cast<const uint4*>(h1row + kc*32 + lg*8);
        const uint4 ub = *reinterpret_cast<const uint4*>(h1row + kc*32 + lg*8 + 4);
        bf16x8 a2h, a2l;
        unpack8(ua, ub, a2h, a2l);
        {
            const unsigned short* wL = ldsW + cur*WBUF + l15*WROW + lg*8;
            #pragma unroll
            for (int nt = 0; nt < 8; ++nt) {
                const bf16x8 bh = *(const bf16x8*)(wL + nt*16*WROW);
                const bf16x8 bl = *(const bf16x8*)(wL + WPLANE + nt*16*WROW);
                acc[nt] = __builtin_amdgcn_mfma_f32_16x16x32_bf16(a2h, bh, acc[nt], 0, 0, 0);
                acc[nt] = __builtin_amdgcn_mfma_f32_16x16x32_bf16(a2l, bh, acc[nt], 0, 0, 0);
                acc[nt] = __builtin_amdgcn_mfma_f32_16x16x32_bf16(a2h, bl, acc[nt], 0, 0, 0);
            }
        }
        if (kc < 3) {
            unsigned short* d = ldsW + (cur^1)*WBUF + sp*WPLANE + sn*WROW + sh;
            *reinterpret_cast<uint4*>(d)     = wa;
            *reinterpret_cast<uint4*>(d + 8) = wb;
            __syncthreads();
            cur ^= 1;
        }
    }

    // ---- readout: bias+relu then dot with Wr; reduce over 16 channel lanes ----
    float pr[4][4];
    #pragma unroll
    for (int j = 0; j < 4; ++j)
        #pragma unroll
        for (int q = 0; q < 4; ++q) pr[j][q] = 0.0f;
    #pragma unroll
    for (int nt = 0; nt < 8; ++nt) {
        const int ch = nt * 16 + l15;
        const float bb = b2[ch];
        const float4 wr = *reinterpret_cast<const float4*>(Wr + ch * 4);
        #pragma unroll
        for (int j = 0; j < 4; ++j) {
            const float hv = fmaxf(acc[nt][j] + bb, 0.0f);
            pr[j][0] = fmaf(hv, wr.x, pr[j][0]);
            pr[j][1] = fmaf(hv, wr.y, pr[j][1]);
            pr[j][2] = fmaf(hv, wr.z, pr[j][2]);
            pr[j][3] = fmaf(hv, wr.w, pr[j][3]);
        }
    }
    #pragma unroll
    for (int m = 1; m <= 8; m <<= 1)
        #pragma unroll
        for (int j = 0; j < 4; ++j)
            #pragma unroll
            for (int q = 0; q < 4; ++q)
                pr[j][q] += __shfl_xor(pr[j][q], m, 64);
    if (l15 == 0) {
        #pragma unroll
        for (int j = 0; j < 4; ++j) {
            float4 o;
            o.x = pr[j][0]; o.y = pr[j][1]; o.z = pr[j][2]; o.w = pr[j][3];
            *reinterpret_cast<float4*>(&s_part[v][hrbase + j][0]) = o;
        }
    }
    __syncthreads();

    // ---- render inline: wave 0, lane = sample ----
    if (t < NSAMP) {
        const int p = t;
        const float o0 = 0.5f*(s_part[0][p][0] + s_part[1][p][0]) + br[0];
        const float o1 = 0.5f*(s_part[0][p][1] + s_part[1][p][1]) + br[1];
        const float o2 = 0.5f*(s_part[0][p][2] + s_part[1][p][2]) + br[2];
        const float o3 = 0.5f*(s_part[0][p][3] + s_part[1][p][3]) + br[3];
        const float c0 = 1.0f/(1.0f + __expf(-o0));
        const float c1 = 1.0f/(1.0f + __expf(-o1));
        const float c2 = 1.0f/(1.0f + __expf(-o2));
        const float dens = fmaxf(o3, 0.0f);
        const float zp = ZNEAR + p * STEP;
        const float zn = ZNEAR + (p+1) * STEP;
        const float dlast = (ZNEAR + 63*STEP) - (ZNEAR + 62*STEP);
        const float dist = (p == NSAMP-1) ? dlast : (zn - zp);
        const float alpha = 1.0f - __expf(-dens*dist);
        float scan = 1.0f - alpha + 1e-10f;              // inclusive cumprod
        #pragma unroll
        for (int off = 1; off < 64; off <<= 1) {
            const float vsh = __shfl_up(scan, off, 64);
            if (p >= off) scan *= vsh;
        }
        float trans = __shfl_up(scan, 1, 64);            // exclusive
        if (p == 0) trans = 1.0f;
        const float w = alpha * trans;
        float s0 = w*c0, s1 = w*c1, s2 = w*c2, sd = w*zp;
        #pragma unroll
        for (int m = 32; m > 0; m >>= 1) {
            s0 += __shfl_xor(s0, m, 64);
            s1 += __shfl_xor(s1, m, 64);
            s2 += __shfl_xor(s2, m, 64);
            sd += __shfl_xor(sd, m, 64);
        }
        if (p == 0) {
            out[r*3+0] = s0; out[r*3+1] = s1; out[r*3+2] = s2;
            out[NRAYS*3 + r] = sd;
        }
    }
}

extern "C" void kernel_launch(void* const* d_in, const int* in_sizes, int n_in,
                              void* d_out, int out_size, void* d_ws, size_t ws_size,
                              hipStream_t stream) {
    const float* rayo   = (const float*)d_in[0];
    const float* rayd   = (const float*)d_in[1];
    const float* images = (const float*)d_in[2];
    const float* intr   = (const float*)d_in[3];
    const float* einv   = (const float*)d_in[4];
    const float* feats  = (const float*)d_in[5];
    const float* W1     = (const float*)d_in[6];
    const float* b1     = (const float*)d_in[7];
    const float* W2     = (const float*)d_in[8];
    const float* b2     = (const float*)d_in[9];
    const float* Wr     = (const float*)d_in[10];
    const float* br     = (const float*)d_in[11];
    float* out = (float*)d_out;
    unsigned short* wsu = (unsigned short*)d_ws;                 // W split planes (213 KB)

    hipLaunchKernelGGL(nerf_prep, dim3(208), dim3(256), 0, stream, W1, W2, wsu);
    hipLaunchKernelGGL(nerf_main, dim3(NRAYS), dim3(512), 0, stream,
                       rayo, rayd, images, intr, einv, feats, b1, b2, Wr, br, wsu, out);
}